// Round 3
// baseline (151.191 us; speedup 1.0000x reference)
//
#include <hip/hip_runtime.h>

// Lorenz96 RK4, fp32 — redundant-halo + 4-chunk software pipeline:
//   Dense 64-lane mapping (no idle lanes): wave w owns float4s
//   [w*256, w*256+256), thread chunk j at f = w*256 + j*64 + lane ->
//   every load/store instruction is a dense 1KB burst, wave footprint is
//   a contiguous 4KB block.
//   Per chunk, the RK4 stencil window [p-8, p+7] = 4 aligned float4s of
//   the chunk's row (cols c-2,c-1,c,c+1 mod 10) -> redundant-halo compute,
//   zero cross-lane ops, no LDS, no barriers.
//   Pipeline: load chunks 0,1 up front; then {load chunk j+2; compute j;
//   store j}. Keeps independent loads in flight through the whole wave
//   lifetime, cuts wave count 4x (prologue/index amortized), vs the
//   one-shot-per-wave structure that left every pipe <35% busy.

#define FORCE 8.0f

__device__ __forceinline__ float4 rk4_chunk(const float4 vm2, const float4 vm1,
                                            const float4 v0,  const float4 vp1,
                                            const float dt,   const float hdt)
{
    float xa[16];
    xa[0]=vm2.x;  xa[1]=vm2.y;  xa[2]=vm2.z;  xa[3]=vm2.w;
    xa[4]=vm1.x;  xa[5]=vm1.y;  xa[6]=vm1.z;  xa[7]=vm1.w;
    xa[8]=v0.x;   xa[9]=v0.y;   xa[10]=v0.z;  xa[11]=v0.w;
    xa[12]=vp1.x; xa[13]=vp1.y; xa[14]=vp1.z; xa[15]=vp1.w;

    // d[i] = (x[i+1] - x[i-2]) * x[i-1] - x[i] + F; window-relative:
    //   D[i] = (S[i+3] - S[i]) * S[i+1] - S[i+2] + F   (window shrinks by 3)
    float k1[13], y1[13];
#pragma unroll
    for (int i = 0; i < 13; ++i)
        k1[i] = (xa[i+3] - xa[i]) * xa[i+1] - xa[i+2] + FORCE;
#pragma unroll
    for (int i = 0; i < 13; ++i)
        y1[i] = fmaf(hdt, k1[i], xa[i+2]);

    float k2[10], y2[10];
#pragma unroll
    for (int i = 0; i < 10; ++i)
        k2[i] = (y1[i+3] - y1[i]) * y1[i+1] - y1[i+2] + FORCE;
#pragma unroll
    for (int i = 0; i < 10; ++i)
        y2[i] = fmaf(hdt, k2[i], xa[i+4]);

    float k3[7], y3[7];
#pragma unroll
    for (int i = 0; i < 7; ++i)
        k3[i] = (y2[i+3] - y2[i]) * y2[i+1] - y2[i+2] + FORCE;
#pragma unroll
    for (int i = 0; i < 7; ++i)
        y3[i] = fmaf(dt, k3[i], xa[i+6]);

    float k4[4];
#pragma unroll
    for (int i = 0; i < 4; ++i)
        k4[i] = (y3[i+3] - y3[i]) * y3[i+1] - y3[i+2] + FORCE;

    const float sc = dt * (1.0f / 6.0f);
    float4 r;
    {
        float t0 = k1[6] + k4[0]; t0 = fmaf(2.0f, k2[4], t0); t0 = fmaf(2.0f, k3[2], t0);
        float t1 = k1[7] + k4[1]; t1 = fmaf(2.0f, k2[5], t1); t1 = fmaf(2.0f, k3[3], t1);
        float t2 = k1[8] + k4[2]; t2 = fmaf(2.0f, k2[6], t2); t2 = fmaf(2.0f, k3[4], t2);
        float t3 = k1[9] + k4[3]; t3 = fmaf(2.0f, k2[7], t3); t3 = fmaf(2.0f, k3[5], t3);
        r.x = fmaf(sc, t0, xa[8]);
        r.y = fmaf(sc, t1, xa[9]);
        r.z = fmaf(sc, t2, xa[10]);
        r.w = fmaf(sc, t3, xa[11]);
    }
    return r;
}

__global__ __launch_bounds__(256)
void lorenz96_rk4_halo4(const float4* __restrict__ x0,
                        const float* __restrict__ dt_p,
                        float4* __restrict__ out,
                        unsigned nf4)   // batch * 10 float4s total (multiple of 10)
{
    const unsigned tid  = blockIdx.x * blockDim.x + threadIdx.x;
    const unsigned w    = tid >> 6;
    const unsigned lane = tid & 63u;
    const unsigned fb   = w * 256u + lane;   // chunk j at fb + 64*j

    const float dt  = dt_p[0];
    const float hdt = 0.5f * dt;

    float4 a0_, a1_, a2_, a3_;   // chunk input registers (4 chunks x 4 f4)
    float4 b0_, b1_, b2_, b3_;
    float4 c0_, c1_, c2_, c3_;
    float4 d0_, d1_, d2_, d3_;
    unsigned f0_, f1_, f2_, f3_;
    bool act0, act1, act2, act3;

#define LOADC(J, A, B, C, D, F, ACT)                                         \
    {                                                                        \
        F = fb + 64u * (J);                                                  \
        ACT = (F < nf4);                                                     \
        if (ACT) {                                                           \
            const unsigned r  = F / 10u;                                     \
            const unsigned c  = F - r * 10u;                                 \
            const unsigned rb = r * 10u;                                     \
            const unsigned cm2 = (c >= 2u) ? c - 2u : c + 8u;                \
            const unsigned cm1 = (c >= 1u) ? c - 1u : c + 9u;                \
            const unsigned cp1 = (c <= 8u) ? c + 1u : c - 9u;                \
            A = x0[rb + cm2];                                                \
            B = x0[rb + cm1];                                                \
            C = x0[rb + c  ];                                                \
            D = x0[rb + cp1];                                                \
        }                                                                    \
    }

#define COMPC(A, B, C, D, F, ACT)                                            \
    if (ACT) { out[F] = rk4_chunk(A, B, C, D, dt, hdt); }

    LOADC(0, a0_, b0_, c0_, d0_, f0_, act0)
    LOADC(1, a1_, b1_, c1_, d1_, f1_, act1)
    LOADC(2, a2_, b2_, c2_, d2_, f2_, act2)
    COMPC(a0_, b0_, c0_, d0_, f0_, act0)
    LOADC(3, a3_, b3_, c3_, d3_, f3_, act3)
    COMPC(a1_, b1_, c1_, d1_, f1_, act1)
    COMPC(a2_, b2_, c2_, d2_, f2_, act2)
    COMPC(a3_, b3_, c3_, d3_, f3_, act3)

#undef LOADC
#undef COMPC
}

extern "C" void kernel_launch(void* const* d_in, const int* in_sizes, int n_in,
                              void* d_out, int out_size, void* d_ws, size_t ws_size,
                              hipStream_t stream) {
    const float4* x0 = (const float4*)d_in[0];
    // d_in[1] = t (unused; autonomous system)
    const float* dt = (const float*)d_in[2];
    float4* out = (float4*)d_out;

    const unsigned nf4 = (unsigned)((long)in_sizes[0] / 4);  // batch*10 float4s
    const unsigned nwaves = (nf4 + 255u) / 256u;             // 256 f4 per wave
    const int block = 256;                                   // 4 waves/block
    const unsigned grid = (nwaves + 3u) / 4u;
    lorenz96_rk4_halo4<<<dim3(grid), dim3(block), 0, stream>>>(x0, dt, out, nf4);
}